// Round 5
// baseline (107.382 us; speedup 1.0000x reference)
//
#include <hip/hip_runtime.h>

#define BB 4
#define CC 32
#define HH 512
#define WW 500
#define SS 10
#define SW 50
#define RROWS 4   // rows per block -> grid = 4 * 512/4 = 512 blocks

// ---------------- Stage 1: strip channel sums + texture energy ----------------
// Block: 640 threads = 10 waves; wave s owns strip s, lanes 0..49 own columns.
// Each lane accumulates 32 per-channel sums + sum of (cross-channel sum)^2
// over RROWS rows, then 64-lane butterfly reduce, then atomicAdd to workspace.
__global__ __launch_bounds__(640, 5)
void pan_stage1(const float* __restrict__ x,
                float* __restrict__ chan,   // [BB][SS][CC]
                float* __restrict__ tex)    // [BB][SS]
{
    const int bid   = blockIdx.x;
    const int b     = bid / (HH / RROWS);
    const int hbase = (bid % (HH / RROWS)) * RROWS;
    const int wave  = threadIdx.x >> 6;   // strip
    const int lane  = threadIdx.x & 63;
    const int s     = wave;
    const int col   = s * SW + lane;
    const bool active = (lane < SW);

    float csum[CC];
#pragma unroll
    for (int c = 0; c < CC; ++c) csum[c] = 0.0f;
    float tsum = 0.0f;

    const float* base = x + (size_t)b * CC * HH * WW;
    for (int r = 0; r < RROWS; ++r) {
        const int h = hbase + r;
        const float* px = base + (size_t)h * WW + col;
        if (active) {
            float gsum = 0.0f;
#pragma unroll
            for (int c = 0; c < CC; ++c) {
                float v = px[(size_t)c * HH * WW];
                csum[c] += v;
                gsum += v;
            }
            tsum += gsum * gsum;
        }
    }

    // 64-lane butterfly reductions (lanes >= 50 hold zeros)
#pragma unroll
    for (int c = 0; c < CC; ++c) {
        float v = csum[c];
#pragma unroll
        for (int off = 32; off >= 1; off >>= 1) v += __shfl_xor(v, off, 64);
        csum[c] = v;
    }
    {
        float v = tsum;
#pragma unroll
        for (int off = 32; off >= 1; off >>= 1) v += __shfl_xor(v, off, 64);
        tsum = v;
    }

    float* cdst = chan + ((b * SS) + s) * CC;
#pragma unroll
    for (int c = 0; c < CC; ++c) {
        if (lane == c) atomicAdd(cdst + c, csum[c]);  // compile-time c: csum stays in regs
    }
    if (lane == 63) atomicAdd(tex + b * SS + s, tsum);
}

// ---------------- Stage 2: feats, hierarchy+reg, pairwise loss, tree ----------------
// 1024 threads: every fill phase except feats (1280) fits in one pass.
__global__ __launch_bounds__(1024)
void pan_stage2(const float* __restrict__ chan,
                const float* __restrict__ tex,
                float* __restrict__ out)
{
    __shared__ float feats[BB][SS][CC];   // 1280
    __shared__ float cur1[BB][5][CC];     // 640
    __shared__ float cur2[BB][3][CC];     // 384
    __shared__ float cur3[BB][2][CC];     // 256
    __shared__ float cur4[BB][1][CC];     // 128
    __shared__ float red[1024];
    const int t = threadIdx.x;

    // feats = 0.5 * nodes + 0.5 * texture   (1280 elements, strided)
    for (int i = t; i < BB * SS * CC; i += 1024) {
        int b = i / (SS * CC);
        int s = (i / CC) % SS;
        float node    = chan[i] * (1.0f / (HH * SW));         // /25600
        float texture = tex[b * SS + s] * (1.0f / (CC * CC)); // tsum/1024
        ((float*)feats)[i] = 0.5f * node + 0.5f * texture;
    }
    __syncthreads();

    if (t < BB * 5 * CC) {   // 640
        int b = t / (5 * CC), j = (t / CC) % 5, c = t % CC;
        cur1[b][j][c] = 0.5f * (feats[b][2 * j][c] + feats[b][2 * j + 1][c]);
    }
    __syncthreads();
    if (t < BB * 3 * CC) {   // 384
        int b = t / (3 * CC), j = (t / CC) % 3, c = t % CC;
        cur2[b][j][c] = (j < 2) ? 0.5f * (cur1[b][2 * j][c] + cur1[b][2 * j + 1][c])
                                : cur1[b][4][c];
    }
    __syncthreads();
    if (t < BB * 2 * CC) {   // 256
        int b = t / (2 * CC), j = (t / CC) % 2, c = t % CC;
        cur3[b][j][c] = (j == 0) ? 0.5f * (cur2[b][0][c] + cur2[b][1][c])
                                 : cur2[b][2][c];
    }
    __syncthreads();
    if (t < BB * CC) {       // 128
        int b = t / CC, c = t % CC;
        cur4[b][0][c] = 0.5f * (cur3[b][0][c] + cur3[b][1][c]);
    }
    __syncthreads();

    // reg = sum of per-level means of cur^2
    float rp = 0.0f;
    for (int i = t; i < BB * 5 * CC; i += 1024) { float v = ((float*)cur1)[i]; rp += v * v * (1.0f / (BB * 5 * CC)); }
    for (int i = t; i < BB * 3 * CC; i += 1024) { float v = ((float*)cur2)[i]; rp += v * v * (1.0f / (BB * 3 * CC)); }
    for (int i = t; i < BB * 2 * CC; i += 1024) { float v = ((float*)cur3)[i]; rp += v * v * (1.0f / (BB * 2 * CC)); }
    for (int i = t; i < BB * 1 * CC; i += 1024) { float v = ((float*)cur4)[i]; rp += v * v * (1.0f / (BB * 1 * CC)); }

    // pairwise contrastive term over leaves (400 pairs)
    float lp = 0.0f;
    if (t < BB * SS * SS) {
        int b = t / (SS * SS), i = (t / SS) % SS, j = t % SS;
        float d2 = 0.0f;
#pragma unroll
        for (int c = 0; c < CC; ++c) {
            float df = feats[b][i][c] - feats[b][j][c];
            d2 += df * df;
        }
        float d = sqrtf(d2 + 1e-12f);
        int lev;
        if (i == j) lev = 0;
        else if ((i >> 1) == (j >> 1)) lev = 1;
        else {
            int g2i = (i < 4) ? 0 : ((i < 8) ? 1 : 2);
            int g2j = (j < 4) ? 0 : ((j < 8) ? 1 : 2);
            if (g2i == g2j) lev = 2;
            else if ((i < 8) == (j < 8)) lev = 3;
            else lev = 4;
        }
        float w = 1.0f - 0.25f * (float)lev;
        float m = fmaxf(1.0f - d, 0.0f);
        lp = w * d * d + (1.0f - w) * m * m;
    }

    // reduce pairwise sum
    red[t] = lp;
    __syncthreads();
    for (int off = 512; off >= 1; off >>= 1) {
        if (t < off) red[t] += red[t + off];
        __syncthreads();
    }
    float lsum = red[0];
    __syncthreads();
    // reduce reg partials
    red[t] = rp;
    __syncthreads();
    for (int off = 512; off >= 1; off >>= 1) {
        if (t < off) red[t] += red[t + off];
        __syncthreads();
    }
    if (t == 0) out[BB * 21 * 2] = lsum * (1.0f / (BB * SS * SS)) + 0.01f * red[0];

    // tree: [B, 21, 2] = (parent, level), written as float32 (168 elements)
    if (t < BB * 21 * 2) {
        int g = (t % 42) >> 1;
        int k = t & 1;
        int par, lv;
        if (g < 10)      { par = 10 + (g >> 1);        lv = 0; }
        else if (g < 15) { par = 15 + ((g - 10) >> 1); lv = 1; }
        else if (g < 18) { par = 18 + ((g - 15) >> 1); lv = 2; }
        else if (g < 20) { par = 20;                   lv = 3; }
        else             { par = 20;                   lv = 4; }
        out[t] = (float)(k ? lv : par);
    }
}

extern "C" void kernel_launch(void* const* d_in, const int* in_sizes, int n_in,
                              void* d_out, int out_size, void* d_ws, size_t ws_size,
                              hipStream_t stream) {
    const float* x = (const float*)d_in[0];
    float* out  = (float*)d_out;
    float* chan = (float*)d_ws;            // 1280 floats
    float* tex  = chan + BB * SS * CC;     // 40 floats

    hipMemsetAsync(d_ws, 0, (BB * SS * CC + BB * SS) * sizeof(float), stream);
    pan_stage1<<<BB * (HH / RROWS), 640, 0, stream>>>(x, chan, tex);
    pan_stage2<<<1, 1024, 0, stream>>>(chan, tex, out);
}

// Round 7
// 66.146 us; speedup vs baseline: 1.6234x; 1.6234x over previous
//
#include <hip/hip_runtime.h>

#define BB 4
#define CC 32
#define HH 512
#define WW 500
#define SS 10
#define SW 50
#define P2 (WW / 2)      // 250 float2 columns per row
#define RPB 4            // rows per block
#define BPB (HH / RPB)   // 128 row-group blocks per batch image

// ---------------- Stage 1: strip channel sums + texture energy ----------------
// Thread owns one float2 column (both elements in ONE strip since SW=50 is even);
// block = 256 threads covers all 250 columns (all 10 strips) for RPB rows.
// Wave loads are 64 lanes x 8B = 512B contiguous. Channel loop fully unrolled,
// rows unrolled x2 -> deep MLP. Reduce via LDS atomics, then global atomics.
__global__ __launch_bounds__(256, 2)
void pan_stage1(const float* __restrict__ x,
                float* __restrict__ chan,   // [BB][SS][CC]
                float* __restrict__ tex)    // [BB][SS]
{
    const int tid = threadIdx.x;
    const int blk = blockIdx.x;
    const int b   = blk / BPB;
    const int r0  = (blk % BPB) * RPB;
    const int p   = tid;                 // float2 column index
    const bool active = (p < P2);
    const int s   = p / (SW / 2);        // strip (25 float2 per strip)

    float csum[CC];
#pragma unroll
    for (int c = 0; c < CC; ++c) csum[c] = 0.0f;
    float tsum = 0.0f;

    if (active) {
        const float* base = x + (size_t)b * CC * HH * WW + (size_t)r0 * WW + 2 * p;
#pragma unroll 2
        for (int r = 0; r < RPB; ++r) {
            float gx = 0.0f, gy = 0.0f;
#pragma unroll
            for (int c = 0; c < CC; ++c) {
                const float2 v = *reinterpret_cast<const float2*>(
                    base + (size_t)c * HH * WW + (size_t)r * WW);
                gx += v.x;
                gy += v.y;
                csum[c] += v.x + v.y;
            }
            tsum += gx * gx + gy * gy;
        }
    }

    __shared__ float lds_c[SS * CC];   // 320 > blockDim: use stride loops!
    __shared__ float lds_t[SS];
    for (int i = tid; i < SS * CC; i += 256) lds_c[i] = 0.0f;
    if (tid < SS) lds_t[tid] = 0.0f;
    __syncthreads();

    if (active) {
#pragma unroll
        for (int c = 0; c < CC; ++c) atomicAdd(&lds_c[s * CC + c], csum[c]);
        atomicAdd(&lds_t[s], tsum);
    }
    __syncthreads();

    for (int i = tid; i < SS * CC; i += 256) atomicAdd(chan + b * SS * CC + i, lds_c[i]);
    if (tid < SS) atomicAdd(tex + b * SS + tid, lds_t[tid]);
}

// ---------------- Stage 2: feats, hierarchy+reg, pairwise loss, tree ----------------
// 1024 threads: every fill phase except feats (1280) fits in one pass.
__global__ __launch_bounds__(1024)
void pan_stage2(const float* __restrict__ chan,
                const float* __restrict__ tex,
                float* __restrict__ out)
{
    __shared__ float feats[BB][SS][CC];   // 1280
    __shared__ float cur1[BB][5][CC];     // 640
    __shared__ float cur2[BB][3][CC];     // 384
    __shared__ float cur3[BB][2][CC];     // 256
    __shared__ float cur4[BB][1][CC];     // 128
    __shared__ float red[1024];
    const int t = threadIdx.x;

    // feats = 0.5 * nodes + 0.5 * texture   (1280 elements, strided)
    for (int i = t; i < BB * SS * CC; i += 1024) {
        int b = i / (SS * CC);
        int s = (i / CC) % SS;
        float node    = chan[i] * (1.0f / (HH * SW));         // /25600
        float texture = tex[b * SS + s] * (1.0f / (CC * CC)); // tsum/1024
        ((float*)feats)[i] = 0.5f * node + 0.5f * texture;
    }
    __syncthreads();

    if (t < BB * 5 * CC) {   // 640
        int b = t / (5 * CC), j = (t / CC) % 5, c = t % CC;
        cur1[b][j][c] = 0.5f * (feats[b][2 * j][c] + feats[b][2 * j + 1][c]);
    }
    __syncthreads();
    if (t < BB * 3 * CC) {   // 384
        int b = t / (3 * CC), j = (t / CC) % 3, c = t % CC;
        cur2[b][j][c] = (j < 2) ? 0.5f * (cur1[b][2 * j][c] + cur1[b][2 * j + 1][c])
                                : cur1[b][4][c];
    }
    __syncthreads();
    if (t < BB * 2 * CC) {   // 256
        int b = t / (2 * CC), j = (t / CC) % 2, c = t % CC;
        cur3[b][j][c] = (j == 0) ? 0.5f * (cur2[b][0][c] + cur2[b][1][c])
                                 : cur2[b][2][c];
    }
    __syncthreads();
    if (t < BB * CC) {       // 128
        int b = t / CC, c = t % CC;
        cur4[b][0][c] = 0.5f * (cur3[b][0][c] + cur3[b][1][c]);
    }
    __syncthreads();

    // reg = sum of per-level means of cur^2
    float rp = 0.0f;
    for (int i = t; i < BB * 5 * CC; i += 1024) { float v = ((float*)cur1)[i]; rp += v * v * (1.0f / (BB * 5 * CC)); }
    for (int i = t; i < BB * 3 * CC; i += 1024) { float v = ((float*)cur2)[i]; rp += v * v * (1.0f / (BB * 3 * CC)); }
    for (int i = t; i < BB * 2 * CC; i += 1024) { float v = ((float*)cur3)[i]; rp += v * v * (1.0f / (BB * 2 * CC)); }
    for (int i = t; i < BB * 1 * CC; i += 1024) { float v = ((float*)cur4)[i]; rp += v * v * (1.0f / (BB * 1 * CC)); }

    // pairwise contrastive term over leaves (400 pairs)
    float lp = 0.0f;
    if (t < BB * SS * SS) {
        int b = t / (SS * SS), i = (t / SS) % SS, j = t % SS;
        float d2 = 0.0f;
#pragma unroll
        for (int c = 0; c < CC; ++c) {
            float df = feats[b][i][c] - feats[b][j][c];
            d2 += df * df;
        }
        float d = sqrtf(d2 + 1e-12f);
        int lev;
        if (i == j) lev = 0;
        else if ((i >> 1) == (j >> 1)) lev = 1;
        else {
            int g2i = (i < 4) ? 0 : ((i < 8) ? 1 : 2);
            int g2j = (j < 4) ? 0 : ((j < 8) ? 1 : 2);
            if (g2i == g2j) lev = 2;
            else if ((i < 8) == (j < 8)) lev = 3;
            else lev = 4;
        }
        float w = 1.0f - 0.25f * (float)lev;
        float m = fmaxf(1.0f - d, 0.0f);
        lp = w * d * d + (1.0f - w) * m * m;
    }

    // reduce pairwise sum
    red[t] = lp;
    __syncthreads();
    for (int off = 512; off >= 1; off >>= 1) {
        if (t < off) red[t] += red[t + off];
        __syncthreads();
    }
    float lsum = red[0];
    __syncthreads();
    // reduce reg partials
    red[t] = rp;
    __syncthreads();
    for (int off = 512; off >= 1; off >>= 1) {
        if (t < off) red[t] += red[t + off];
        __syncthreads();
    }
    if (t == 0) out[BB * 21 * 2] = lsum * (1.0f / (BB * SS * SS)) + 0.01f * red[0];

    // tree: [B, 21, 2] = (parent, level), written as float32 (168 elements)
    if (t < BB * 21 * 2) {
        int g = (t % 42) >> 1;
        int k = t & 1;
        int par, lv;
        if (g < 10)      { par = 10 + (g >> 1);        lv = 0; }
        else if (g < 15) { par = 15 + ((g - 10) >> 1); lv = 1; }
        else if (g < 18) { par = 18 + ((g - 15) >> 1); lv = 2; }
        else if (g < 20) { par = 20;                   lv = 3; }
        else             { par = 20;                   lv = 4; }
        out[t] = (float)(k ? lv : par);
    }
}

extern "C" void kernel_launch(void* const* d_in, const int* in_sizes, int n_in,
                              void* d_out, int out_size, void* d_ws, size_t ws_size,
                              hipStream_t stream) {
    const float* x = (const float*)d_in[0];
    float* out  = (float*)d_out;
    float* chan = (float*)d_ws;            // 1280 floats
    float* tex  = chan + BB * SS * CC;     // 40 floats

    hipMemsetAsync(d_ws, 0, (BB * SS * CC + BB * SS) * sizeof(float), stream);
    pan_stage1<<<BB * BPB, 256, 0, stream>>>(x, chan, tex);
    pan_stage2<<<1, 1024, 0, stream>>>(chan, tex, out);
}